// Round 5
// baseline (54.300 us; speedup 1.0000x reference)
//
#include <hip/hip_runtime.h>
#include <math.h>

#define BB 4
#define SS 4096
#define HH 2048

typedef float vf4 __attribute__((ext_vector_type(4)));

__device__ __forceinline__ bool is_hit(int v) {
    return (v == 5) || (v == 13) || (v == 42) || (v == 99);
}

// Fused kernel: 256 threads = 4 waves per block; wave w owns row blockIdx.x*4+w.
// Per wave (64 lanes), row = (b,s) of H=2048 floats:
//  - payload: 8x vf4 NT loads (32 floats/lane) -> sum-of-squares -> shfl_xor reduce
//  - trigger: m[s] = 0.95^(s - last_hit_idx<=s); backward 64-wide ballot windows
//    over the L2-resident id row (16KB/batch). Expected ~4.4 windows (P(hit)=4/1000);
//    capped at 16 windows since 0.95^960 ~ 4e-22 << tolerance.
//  - write scaled row + mask scalar. No LDS, no __syncthreads, no scratch.
// 4 waves/block dodges the small-workgroup-per-CU cap that halved occupancy in R4.
__global__ __launch_bounds__(256) void fused_kernel(const float* __restrict__ h,
                                                    const int* __restrict__ ids,
                                                    const float* __restrict__ w,
                                                    float* __restrict__ out_h,
                                                    float* __restrict__ out_m) {
    const int lane = threadIdx.x & 63;
    const int wid = threadIdx.x >> 6;
    const int row = (blockIdx.x << 2) + wid;   // b*SS + s
    const int s = row & (SS - 1);
    const int b = row >> 12;

    const size_t off = (size_t)row * HH;
    const vf4* hp = (const vf4*)(h + off);

    vf4 r[8];
    #pragma unroll
    for (int k = 0; k < 8; ++k)
        r[k] = __builtin_nontemporal_load(&hp[lane + (k << 6)]);

    // trigger search while loads are in flight (independent address stream)
    const int* idrow = ids + ((size_t)b << 12);
    int j = -1;
    #pragma unroll 1
    for (int wnd = 0; wnd < 16; ++wnd) {
        int hi = s - (wnd << 6);           // highest index in this window
        int idx = hi - lane;
        bool hit = (idx >= 0) && is_hit(idrow[idx]);
        unsigned long long m = __ballot(hit);
        if (m) { j = hi - (int)__builtin_ctzll(m); break; }  // lowest lane = largest idx
        if (hi - 63 <= 0) break;           // reached row start
    }
    const float LOG2_DECAY = -0.07400058144377693f;  // log2(0.95)
    float trigv = (j < 0) ? 0.0f : exp2f((float)(s - j) * LOG2_DECAY);

    float ss = 0.0f;
    #pragma unroll
    for (int k = 0; k < 8; ++k)
        ss += r[k].x * r[k].x + r[k].y * r[k].y + r[k].z * r[k].z + r[k].w * r[k].w;

    #pragma unroll
    for (int d = 32; d > 0; d >>= 1) ss += __shfl_xor(ss, d);

    float norm = sqrtf(ss);
    float dn = fmaxf(norm, 1e-12f);
    float sim = ss / (dn * dn);
    sim = fminf(fmaxf(sim, 0.0f), 1.0f);
    float payload = ((1.0f - sim) > 0.5f) ? 1.0f : 0.0f;
    float combined = fmaxf(trigv, payload);
    float maskv = 1.0f - combined * w[0];

    vf4* op = (vf4*)(out_h + off);
    #pragma unroll
    for (int k = 0; k < 8; ++k) {
        vf4 v = r[k] * maskv;
        __builtin_nontemporal_store(v, &op[lane + (k << 6)]);
    }
    if (lane == 0) out_m[row] = maskv;
}

extern "C" void kernel_launch(void* const* d_in, const int* in_sizes, int n_in,
                              void* d_out, int out_size, void* d_ws, size_t ws_size,
                              hipStream_t stream) {
    const float* hidden = (const float*)d_in[0];
    const int* ids = (const int*)d_in[1];
    const float* w = (const float*)d_in[2];

    float* out_h = (float*)d_out;                    // B*S*H floats
    float* out_m = out_h + (size_t)BB * SS * HH;     // B*S floats

    fused_kernel<<<(BB * SS) / 4, 256, 0, stream>>>(hidden, ids, w, out_h, out_m);
}

// Round 6
// 45.994 us; speedup vs baseline: 1.1806x; 1.1806x over previous
//
#include <hip/hip_runtime.h>
#include <math.h>

#define BB 4
#define SS 4096
#define HH 2048

typedef float vf4 __attribute__((ext_vector_type(4)));

__device__ __forceinline__ bool is_hit(int v) {
    return (v == 5) || (v == 13) || (v == 42) || (v == 99);
}

// Fused: 256 threads = 4 waves/block; wave w owns row blockIdx.x*4+w.
// Cache policy (the R4/R5 lesson): REGULAR loads for hidden (128 MiB fits L3,
// re-read every replay -> keep resident); NT stores for output (write-once,
// don't evict the input from L3). No LDS, no __syncthreads, no scratch.
__global__ __launch_bounds__(256) void fused_kernel(const float* __restrict__ h,
                                                    const int* __restrict__ ids,
                                                    const float* __restrict__ w,
                                                    float* __restrict__ out_h,
                                                    float* __restrict__ out_m) {
    const int lane = threadIdx.x & 63;
    const int wid = threadIdx.x >> 6;
    const int row = (blockIdx.x << 2) + wid;   // b*SS + s
    const int s = row & (SS - 1);
    const int b = row >> 12;

    // ---- trigger: backward ballot search for last hit (serial chain ~4.4
    // L2-resident windows; issued first so row loads overlap it) ----
    const int* idrow = ids + ((size_t)b << 12);
    int j = -1;
    #pragma unroll 1
    for (int wnd = 0; wnd < 16; ++wnd) {
        int hi = s - (wnd << 6);
        int idx = hi - lane;
        bool hit = (idx >= 0) && is_hit(idrow[idx]);
        unsigned long long m = __ballot(hit);
        if (m) { j = hi - (int)__builtin_ctzll(m); break; }
        if (hi - 63 <= 0) break;
    }
    const float LOG2_DECAY = -0.07400058144377693f;  // log2(0.95)
    float trigv = (j < 0) ? 0.0f : exp2f((float)(s - j) * LOG2_DECAY);

    // ---- payload: row sum-of-squares (32 floats/lane in registers) ----
    const size_t off = (size_t)row * HH;
    const vf4* hp = (const vf4*)(h + off);

    vf4 r[8];
    #pragma unroll
    for (int k = 0; k < 8; ++k) r[k] = hp[lane + (k << 6)];

    float ss = 0.0f;
    #pragma unroll
    for (int k = 0; k < 8; ++k)
        ss += r[k].x * r[k].x + r[k].y * r[k].y + r[k].z * r[k].z + r[k].w * r[k].w;

    #pragma unroll
    for (int d = 32; d > 0; d >>= 1) ss += __shfl_xor(ss, d);

    float norm = sqrtf(ss);
    float dn = fmaxf(norm, 1e-12f);
    float sim = ss / (dn * dn);
    sim = fminf(fmaxf(sim, 0.0f), 1.0f);
    float payload = ((1.0f - sim) > 0.5f) ? 1.0f : 0.0f;
    float combined = fmaxf(trigv, payload);
    float maskv = 1.0f - combined * w[0];

    vf4* op = (vf4*)(out_h + off);
    #pragma unroll
    for (int k = 0; k < 8; ++k) {
        vf4 v = r[k] * maskv;
        __builtin_nontemporal_store(v, &op[lane + (k << 6)]);
    }
    if (lane == 0) out_m[row] = maskv;
}

extern "C" void kernel_launch(void* const* d_in, const int* in_sizes, int n_in,
                              void* d_out, int out_size, void* d_ws, size_t ws_size,
                              hipStream_t stream) {
    const float* hidden = (const float*)d_in[0];
    const int* ids = (const int*)d_in[1];
    const float* w = (const float*)d_in[2];

    float* out_h = (float*)d_out;                    // B*S*H floats
    float* out_m = out_h + (size_t)BB * SS * HH;     // B*S floats

    fused_kernel<<<(BB * SS) / 4, 256, 0, stream>>>(hidden, ids, w, out_h, out_m);
}